// Round 1
// baseline (2273.375 us; speedup 1.0000x reference)
//
#include <hip/hip_runtime.h>
#include <math.h>

#define P 512
#define KC 10
#define NB 32
#define EPSV 0.01f

// ---------------- metadata kernels ----------------

__global__ __launch_bounds__(64) void meta_zero(int* counts, int* cursors){
  int t = threadIdx.x;
  if (t < KC){ counts[t] = 0; cursors[t] = 0; }
}

__global__ __launch_bounds__(256) void hist_k(const int* __restrict__ Y, int* counts, int m){
  int i = blockIdx.x * 256 + threadIdx.x;
  if (i < m){
    int y = Y[i];
    if (y >= 0 && y < KC) atomicAdd(&counts[y], 1);
  }
}

__global__ __launch_bounds__(64) void offsets_k(const int* __restrict__ counts, int* offsets){
  if (threadIdx.x == 0){
    int s = 0;
    for (int j = 0; j < KC; ++j){ offsets[j] = s; s += counts[j]; }
    offsets[KC] = s;
  }
}

__global__ __launch_bounds__(256) void scatter_k(const int* __restrict__ Y, const int* __restrict__ offsets,
                                                 int* cursors, int* __restrict__ perm, int m){
  int i = blockIdx.x * 256 + threadIdx.x;
  if (i < m){
    int y = Y[i];
    if (y >= 0 && y < KC){
      int pos = offsets[y] + atomicAdd(&cursors[y], 1);
      perm[pos] = i;
    }
  }
}

// ---------------- per-class Gram (lower-triangle 64x64 tiles) ----------------
// grid: (36, KC). Block 256 = 16x16 threads, 4x4 outputs/thread.
__global__ __launch_bounds__(256) void gram_k(const float* __restrict__ X,
                                              const int* __restrict__ perm,
                                              const int* __restrict__ offsets,
                                              float* __restrict__ Gk){
  __shared__ float As[16][64];
  __shared__ float Bs[16][64];

  int cls = blockIdx.y;
  // map linear tile idx -> (ta, tb), ta >= tb, 8x8 tile grid
  int ta = 0, rem = blockIdx.x;
  while (rem >= ta + 1){ rem -= ta + 1; ++ta; }
  int tb = rem;
  int a0 = ta * 64, b0 = tb * 64;
  bool diag = (ta == tb);

  int start = offsets[cls];
  int n = offsets[cls + 1] - start;

  int tid = threadIdx.x;
  int tx = tid & 15, ty = tid >> 4;

  float acc[4][4];
  #pragma unroll
  for (int i = 0; i < 4; ++i)
    #pragma unroll
    for (int j = 0; j < 4; ++j) acc[i][j] = 0.f;

  int c = tid & 63;
  int kb = tid >> 6;   // 0..3

  for (int r0 = 0; r0 < n; r0 += 16){
    #pragma unroll
    for (int it = 0; it < 4; ++it){
      int kk = it * 4 + kb;
      int r = r0 + kk;
      float va = 0.f, vb = 0.f;
      if (r < n){
        int row = perm[start + r];
        const float* xp = X + (long)row * P;
        va = xp[a0 + c];
        if (!diag) vb = xp[b0 + c];
      }
      As[kk][c] = va;
      if (!diag) Bs[kk][c] = vb;
    }
    __syncthreads();
    const float (*Bp)[64] = diag ? As : Bs;
    #pragma unroll
    for (int kk = 0; kk < 16; ++kk){
      float4 a4 = *(const float4*)&As[kk][ty * 4];
      float4 b4 = *(const float4*)&Bp[kk][tx * 4];
      float av[4] = {a4.x, a4.y, a4.z, a4.w};
      float bv[4] = {b4.x, b4.y, b4.z, b4.w};
      #pragma unroll
      for (int i = 0; i < 4; ++i)
        #pragma unroll
        for (int j = 0; j < 4; ++j)
          acc[i][j] += av[i] * bv[j];
    }
    __syncthreads();
  }

  float* C = Gk + (long)cls * P * P;
  #pragma unroll
  for (int i = 0; i < 4; ++i){
    int a = a0 + ty * 4 + i;
    #pragma unroll
    for (int j = 0; j < 4; ++j){
      int b = b0 + tx * 4 + j;
      C[a * P + b] = acc[i][j];
    }
  }
}

// ---------------- form A_j = I + s_j*Gk_j (in place, lower tri); slot 10 = I + scal*sum ----------------
__global__ __launch_bounds__(256) void formA_k(float* __restrict__ Gk, const int* __restrict__ counts, float m_tot){
  int idx = blockIdx.x * 256 + threadIdx.x;
  int r = idx >> 9, cc = idx & (P - 1);
  if (cc > r) return;
  long off = (long)r * P + cc;
  float diag = (r == cc) ? 1.f : 0.f;
  float g = 0.f;
  #pragma unroll
  for (int j = 0; j < KC; ++j){
    float v = Gk[(long)j * P * P + off];
    g += v;
    float trPi = (float)counts[j] + 1e-8f;
    float s = (float)P / (trPi * EPSV);
    Gk[(long)j * P * P + off] = diag + s * v;
  }
  float scal = (float)P / (m_tot * EPSV);
  Gk[(long)KC * P * P + off] = diag + scal * g;
}

// ---------------- batched blocked Cholesky logdet (lower triangle in global) ----------------
// 11 blocks of 256 threads. Panel (NB=32 cols) staged in LDS with XOR swizzle:
//   Lp(i,u) at i*NB + (u ^ (i & 31))   -> conflict-free column & staging access.
__global__ __launch_bounds__(256) void chol_k(float* __restrict__ Amats, float* __restrict__ logdets){
  __shared__ float Lp[NB * P];   // 64 KiB exactly
  float* A = Amats + (long)blockIdx.x * P * P;
  int tid = threadIdx.x;
  float logsum = 0.f;

  for (int j0 = 0; j0 < P; j0 += NB){
    int q = P - j0;
    // ---- stage panel rows j0..P-1, cols j0..j0+NB-1 ----
    for (int idx = tid; idx < q * NB; idx += 256){
      int rr = idx >> 5;
      int u  = idx & 31;
      int i  = j0 + rr;
      Lp[i * NB + (u ^ (i & 31))] = A[(long)i * P + j0 + u];
    }
    __syncthreads();

    // ---- factor panel (left-looking within panel) ----
    for (int jj = 0; jj < NB; ++jj){
      int j = j0 + jj;
      float accv[2]; int ownv[2]; int nown = 0;
      int jbase = j * NB, jm = j & 31;
      for (int i = j + tid; i < P; i += 256){
        int ib = i * NB, im = i & 31;
        float acc0 = Lp[ib + (jj ^ im)];
        float acc1 = 0.f;
        int u = 0;
        for (; u + 1 < jj; u += 2){
          acc0 -= Lp[ib + (u ^ im)] * Lp[jbase + (u ^ jm)];
          acc1 -= Lp[ib + ((u + 1) ^ im)] * Lp[jbase + ((u + 1) ^ jm)];
        }
        if (u < jj) acc0 -= Lp[ib + (u ^ im)] * Lp[jbase + (u ^ jm)];
        float acc = acc0 + acc1;
        Lp[ib + (jj ^ im)] = acc;   // unscaled (pivot row included)
        accv[nown] = acc; ownv[nown] = i; ++nown;
      }
      __syncthreads();
      float d = Lp[jbase + (jj ^ jm)];
      if (tid == 0) logsum += logf(d);
      float rs = rsqrtf(d);
      for (int t2 = 0; t2 < nown; ++t2){
        int i = ownv[t2];
        Lp[i * NB + (jj ^ (i & 31))] = accv[t2] * rs;
      }
      __syncthreads();
    }

    // ---- trailing update: A[i][l] -= sum_u L[i][u]*L[l][u], i,l >= j1, l <= i ----
    int j1 = j0 + NB;
    if (j1 < P){
      int tx = tid & 15, ty = tid >> 4;
      for (int ti0 = j1; ti0 < P; ti0 += 128){
        for (int tl0 = j1; tl0 <= ti0; tl0 += 128){
          float accC[8][8];
          #pragma unroll
          for (int r = 0; r < 8; ++r)
            #pragma unroll
            for (int c2 = 0; c2 < 8; ++c2) accC[r][c2] = 0.f;

          for (int u = 0; u < NB; ++u){
            float a8[8], b8[8];
            #pragma unroll
            for (int r = 0; r < 8; ++r){
              int i = ti0 + ty + 16 * r;      // strided mapping: conflict-free banks
              a8[r] = (i < P) ? Lp[i * NB + (u ^ (i & 31))] : 0.f;
            }
            #pragma unroll
            for (int c2 = 0; c2 < 8; ++c2){
              int l = tl0 + tx + 16 * c2;
              b8[c2] = (l < P) ? Lp[l * NB + (u ^ (l & 31))] : 0.f;
            }
            #pragma unroll
            for (int r = 0; r < 8; ++r)
              #pragma unroll
              for (int c2 = 0; c2 < 8; ++c2)
                accC[r][c2] += a8[r] * b8[c2];
          }

          #pragma unroll
          for (int r = 0; r < 8; ++r){
            int i = ti0 + ty + 16 * r;
            if (i >= P) continue;
            #pragma unroll
            for (int c2 = 0; c2 < 8; ++c2){
              int l = tl0 + tx + 16 * c2;
              if (l < P && l <= i)
                A[(long)i * P + l] -= accC[r][c2];
            }
          }
        }
      }
    }
    __syncthreads();   // panel LDS reuse + make global syrk writes visible in-block
  }

  if (tid == 0) logdets[blockIdx.x] = logsum;
}

// ---------------- final reduction ----------------
__global__ __launch_bounds__(64) void final_k(const float* __restrict__ logdets,
                                              const int* __restrict__ counts,
                                              float* __restrict__ out, float m_tot){
  if (threadIdx.x == 0 && blockIdx.x == 0){
    out[0] = 0.5f * logdets[KC];
    float comp = 0.f;
    for (int j = 0; j < KC; ++j){
      float trPi = (float)counts[j] + 1e-8f;
      comp += logdets[j] * trPi / m_tot;
    }
    out[1] = 0.5f * comp;
  }
}

extern "C" void kernel_launch(void* const* d_in, const int* in_sizes, int n_in,
                              void* d_out, int out_size, void* d_ws, size_t ws_size,
                              hipStream_t stream) {
  (void)n_in; (void)out_size; (void)ws_size;
  const float* X = (const float*)d_in[0];
  const int*   Y = (const int*)d_in[1];
  int m = in_sizes[0] / P;     // 16384

  float* Gk      = (float*)d_ws;                 // 11 * P*P floats
  int*   perm    = (int*)(Gk + 11L * P * P);     // m ints
  int*   counts  = perm + m;                     // 16
  int*   cursors = counts + 16;                  // 16
  int*   offsets = cursors + 16;                 // 16
  float* logdets = (float*)(offsets + 16);       // 11

  meta_zero<<<1, 64, 0, stream>>>(counts, cursors);
  hist_k<<<(m + 255) / 256, 256, 0, stream>>>(Y, counts, m);
  offsets_k<<<1, 64, 0, stream>>>(counts, offsets);
  scatter_k<<<(m + 255) / 256, 256, 0, stream>>>(Y, offsets, cursors, perm, m);

  dim3 gg(36, KC);
  gram_k<<<gg, 256, 0, stream>>>(X, perm, offsets, Gk);

  formA_k<<<(P * P) / 256, 256, 0, stream>>>(Gk, counts, (float)m);

  chol_k<<<KC + 1, 256, 0, stream>>>(Gk, logdets);

  final_k<<<1, 64, 0, stream>>>(logdets, counts, (float*)d_out, (float)m);
}